// Round 6
// baseline (219.131 us; speedup 1.0000x reference)
//
#include <hip/hip_runtime.h>
#include <hip/hip_bf16.h>
#include <math.h>

#define N_TOKENS 32768
#define HIDDEN   2048
#define NEXP     8
#define H4       (HIDDEN / 4)            // 512 float4 per row
#define BLOCK    1024                    // 16 waves
#define WPB      (BLOCK / 64)
#define TOK_PER_WAVE 4
#define GRID     (N_TOKENS / (WPB * TOK_PER_WAVE))   // 512 blocks

#define SCORES_OFF 0
#define IDX_OFF    (N_TOKENS * 2)        // 65536
#define HIST_OFF   (N_TOKENS * 4)        // 131072

__global__ void zero_hist_kernel(float* out) {
    if (threadIdx.x < NEXP) out[HIST_OFF + threadIdx.x] = 0.0f;
}

__device__ __forceinline__ void emit_token(const double* acc, int t,
                                           float* __restrict__ out, int* cnt) {
    // top-2 with lowest-index tie-break (strict >), matching jax.lax.top_k
    double b1 = acc[0]; int i1 = 0;
    double b2 = -1.0e300; int i2 = 0;
#pragma unroll
    for (int e = 1; e < NEXP; ++e) {
        double v = acc[e];
        if (v > b1)      { b2 = b1; i2 = i1; b1 = v; i1 = e; }
        else if (v > b2) { b2 = v;  i2 = e; }
    }
    float d  = (float)(b2 - b1);
    float e1 = expf(d);
    float s0 = 1.0f / (1.0f + e1);

    float2 sc; sc.x = s0; sc.y = e1 * s0;
    float2 ix; ix.x = (float)i1; ix.y = (float)i2;
    *reinterpret_cast<float2*>(out + SCORES_OFF + 2 * t) = sc;
    *reinterpret_cast<float2*>(out + IDX_OFF    + 2 * t) = ix;

#pragma unroll
    for (int e = 0; e < NEXP; ++e) cnt[e] += (i1 == e) + (i2 == e);
}

// round-3 structure (wave-owns-token, W in LDS, coalesced x->regs) +
// depth-2 register prefetch + reduce-scatter butterfly (bit-identical sums).
__global__ __launch_bounds__(BLOCK, 4) void router_kernel(
        const float* __restrict__ x, const float* __restrict__ W,
        float* __restrict__ out) {
    __shared__ float4 wlds[NEXP * H4];   // 64 KiB

    const int tid = threadIdx.x;
    const float4* Wv = reinterpret_cast<const float4*>(W);
#pragma unroll
    for (int i = 0; i < (NEXP * H4) / BLOCK; ++i)
        wlds[tid + i * BLOCK] = Wv[tid + i * BLOCK];
    __syncthreads();

    const int wave = tid >> 6;
    const int lane = tid & 63;
    const int gw   = blockIdx.x * WPB + wave;

    int cnt[NEXP] = {0, 0, 0, 0, 0, 0, 0, 0};

#pragma unroll 1
    for (int p = 0; p < TOK_PER_WAVE / 2; ++p) {
        const int t0 = gw * TOK_PER_WAVE + 2 * p;
        const float4* xa = reinterpret_cast<const float4*>(x) + (size_t)t0 * H4;
        const float4* xb = xa + H4;

        // acc[0..7] = token a, acc[8..15] = token b
        double acc[16];
#pragma unroll
        for (int e = 0; e < 16; ++e) acc[e] = 0.0;

        // prefetch iterations 0 and 1
        float4 aA = xa[lane];      float4 bA = xb[lane];
        float4 aB = xa[lane + 64]; float4 bB = xb[lane + 64];

#pragma unroll 1
        for (int k2 = 0; k2 < 4; ++k2) {
            float4 aC, bC, aD, bD;
            if (k2 < 3) {   // issue loads for iters 2k2+2, 2k2+3 before computing
                aC = xa[lane + (2 * k2 + 2) * 64]; bC = xb[lane + (2 * k2 + 2) * 64];
                aD = xa[lane + (2 * k2 + 3) * 64]; bD = xb[lane + (2 * k2 + 3) * 64];
            }
            const int k0 = 2 * k2;
#pragma unroll
            for (int e = 0; e < NEXP; ++e) {
                const float4 w = wlds[e * H4 + lane + k0 * 64];
                float s0 = w.x * aA.x;
                s0 = fmaf(w.y, aA.y, s0); s0 = fmaf(w.z, aA.z, s0); s0 = fmaf(w.w, aA.w, s0);
                acc[e] += (double)s0;
                float s1 = w.x * bA.x;
                s1 = fmaf(w.y, bA.y, s1); s1 = fmaf(w.z, bA.z, s1); s1 = fmaf(w.w, bA.w, s1);
                acc[8 + e] += (double)s1;
            }
#pragma unroll
            for (int e = 0; e < NEXP; ++e) {
                const float4 w = wlds[e * H4 + lane + (k0 + 1) * 64];
                float s0 = w.x * aB.x;
                s0 = fmaf(w.y, aB.y, s0); s0 = fmaf(w.z, aB.z, s0); s0 = fmaf(w.w, aB.w, s0);
                acc[e] += (double)s0;
                float s1 = w.x * bB.x;
                s1 = fmaf(w.y, bB.y, s1); s1 = fmaf(w.z, bB.z, s1); s1 = fmaf(w.w, bB.w, s1);
                acc[8 + e] += (double)s1;
            }
            if (k2 < 3) { aA = aC; bA = bC; aB = aD; bB = bD; }
        }

        // reduce-scatter butterfly: masks 1,2,4,8 halve 16 values/lane -> 1,
        // then 16,32 finish. Same pairing & commutative adds => bit-identical
        // totals to the plain butterfly that passed rounds 2-3.
        {
            const bool u1 = lane & 1;
#pragma unroll
            for (int i = 0; i < 8; ++i) {
                double send = u1 ? acc[i] : acc[8 + i];
                double got  = __shfl_xor(send, 1, 64);
                acc[i] = (u1 ? acc[8 + i] : acc[i]) + got;
            }
            const bool u2 = lane & 2;
#pragma unroll
            for (int i = 0; i < 4; ++i) {
                double send = u2 ? acc[i] : acc[4 + i];
                double got  = __shfl_xor(send, 2, 64);
                acc[i] = (u2 ? acc[4 + i] : acc[i]) + got;
            }
            const bool u4 = lane & 4;
#pragma unroll
            for (int i = 0; i < 2; ++i) {
                double send = u4 ? acc[i] : acc[2 + i];
                double got  = __shfl_xor(send, 4, 64);
                acc[i] = (u4 ? acc[2 + i] : acc[i]) + got;
            }
            const bool u8 = lane & 8;
            {
                double send = u8 ? acc[0] : acc[1];
                double got  = __shfl_xor(send, 8, 64);
                acc[0] = (u8 ? acc[1] : acc[0]) + got;
            }
            acc[0] += __shfl_xor(acc[0], 16, 64);
            acc[0] += __shfl_xor(acc[0], 32, 64);
        }
        // lane holding value j satisfies lane&15 == bitrev4(j):
        //   token a (j=e):   lane r = ((e&1)<<3)|((e&2)<<1)|((e&4)>>1)
        //   token b (j=8+e): lane r+1
        double v0[NEXP], v1[NEXP];
#pragma unroll
        for (int e = 0; e < NEXP; ++e) {
            const int r = ((e & 1) << 3) | ((e & 2) << 1) | ((e & 4) >> 1);
            v0[e] = __shfl(acc[0], r,     64);
            v1[e] = __shfl(acc[0], r + 1, 64);
        }
        if (lane == 0) {
            emit_token(v0, t0,     out, cnt);
            emit_token(v1, t0 + 1, out, cnt);
        }
    }

    // block histogram: reuse wlds as scratch after all waves done with W
    __syncthreads();
    float* h = reinterpret_cast<float*>(wlds);
    if (tid < NEXP) h[tid] = 0.0f;
    __syncthreads();
    if (lane == 0) {
#pragma unroll
        for (int e = 0; e < NEXP; ++e)
            if (cnt[e]) atomicAdd(&h[e], (float)cnt[e]);
    }
    __syncthreads();
    if (tid < NEXP) atomicAdd(&out[HIST_OFF + tid], h[tid]);
}

extern "C" void kernel_launch(void* const* d_in, const int* in_sizes, int n_in,
                              void* d_out, int out_size, void* d_ws, size_t ws_size,
                              hipStream_t stream) {
    const float* x = (const float*)d_in[0];
    const float* W = (const float*)d_in[1];
    float* out = (float*)d_out;

    zero_hist_kernel<<<1, 64, 0, stream>>>(out);
    router_kernel<<<GRID, BLOCK, 0, stream>>>(x, W, out);
}

// Round 7
// 62.412 us; speedup vs baseline: 3.5111x; 3.5111x over previous
//
#include <hip/hip_runtime.h>
#include <hip/hip_bf16.h>
#include <math.h>

#define N_TOKENS 32768
#define HIDDEN   2048
#define NEXP     8
#define H4       (HIDDEN / 4)            // 512 float4 per row
#define BLOCK    1024                    // 16 waves
#define WPB      (BLOCK / 64)
#define TOK_PER_WAVE 4
#define GRID     (N_TOKENS / (WPB * TOK_PER_WAVE))   // 512 blocks = 2/CU

#define SCORES_OFF 0
#define IDX_OFF    (N_TOKENS * 2)        // 65536
#define HIST_OFF   (N_TOKENS * 4)        // 131072

__global__ void zero_hist_kernel(float* out) {
    if (threadIdx.x < NEXP) out[HIST_OFF + threadIdx.x] = 0.0f;
}

// top-2 with lowest-index tie-break (strict >), matching jax.lax.top_k.
// cnt: packed 4-bit per-expert counters (max 4 tokens/wave -> fits).
__device__ __forceinline__ void emit_token(const double* acc, int t,
                                           float* __restrict__ out, unsigned* cnt) {
    double b1 = acc[0]; int i1 = 0;
    double b2 = -1.0e300; int i2 = 0;
#pragma unroll
    for (int e = 1; e < NEXP; ++e) {
        double v = acc[e];
        if (v > b1)      { b2 = b1; i2 = i1; b1 = v; i1 = e; }
        else if (v > b2) { b2 = v;  i2 = e; }
    }
    float d  = (float)(b2 - b1);
    float e1 = expf(d);
    float s0 = 1.0f / (1.0f + e1);

    float2 sc; sc.x = s0; sc.y = e1 * s0;
    float2 ix; ix.x = (float)i1; ix.y = (float)i2;
    *reinterpret_cast<float2*>(out + SCORES_OFF + 2 * t) = sc;
    *reinterpret_cast<float2*>(out + IDX_OFF    + 2 * t) = ix;

    *cnt += (1u << (4 * i1)) + (1u << (4 * i2));
}

// Round-3 structure (wave-owns-token-pair, W in LDS, coalesced x->regs),
// designed to the hard 64-VGPR budget the allocator pins at 64KB LDS:
//  - 8-elem f32 dot groups (halves f64 cvt/add; error class proven r4/r5)
//  - reduce-scatter butterfly (17 f64 shuffles vs 96; verified correct r6)
//  - packed histogram counters (1 reg vs 8); no manual prefetch (spilled r6)
__global__ __launch_bounds__(BLOCK, 4) void router_kernel(
        const float* __restrict__ x, const float* __restrict__ W,
        float* __restrict__ out) {
    __shared__ float4 wlds[NEXP * H4];   // 64 KiB

    const int tid = threadIdx.x;
    const float4* Wv = reinterpret_cast<const float4*>(W);
#pragma unroll
    for (int i = 0; i < (NEXP * H4) / BLOCK; ++i)
        wlds[tid + i * BLOCK] = Wv[tid + i * BLOCK];
    __syncthreads();

    const int wave = tid >> 6;
    const int lane = tid & 63;
    const int gw   = blockIdx.x * WPB + wave;

    unsigned cnt = 0;

#pragma unroll 1
    for (int p = 0; p < TOK_PER_WAVE / 2; ++p) {
        const int t0 = gw * TOK_PER_WAVE + 2 * p;
        const float4* xa = reinterpret_cast<const float4*>(x) + (size_t)t0 * H4;
        const float4* xb = xa + H4;

        // acc[0..7] = token a, acc[8..15] = token b
        double acc[16];
#pragma unroll
        for (int e = 0; e < 16; ++e) acc[e] = 0.0;

#pragma unroll 1
        for (int k = 0; k < 8; k += 2) {     // 4 iterations, 8 elems/group
            const float4 a0 = xa[lane + k * 64];
            const float4 a1 = xa[lane + (k + 1) * 64];
            const float4 b0 = xb[lane + k * 64];
            const float4 b1 = xb[lane + (k + 1) * 64];
#pragma unroll
            for (int e = 0; e < NEXP; ++e) {
                const float4 w0 = wlds[e * H4 + lane + k * 64];
                float s0 = w0.x * a0.x;
                s0 = fmaf(w0.y, a0.y, s0); s0 = fmaf(w0.z, a0.z, s0); s0 = fmaf(w0.w, a0.w, s0);
                float s1 = w0.x * b0.x;
                s1 = fmaf(w0.y, b0.y, s1); s1 = fmaf(w0.z, b0.z, s1); s1 = fmaf(w0.w, b0.w, s1);
                const float4 w1 = wlds[e * H4 + lane + (k + 1) * 64];
                s0 = fmaf(w1.x, a1.x, s0); s0 = fmaf(w1.y, a1.y, s0);
                s0 = fmaf(w1.z, a1.z, s0); s0 = fmaf(w1.w, a1.w, s0);
                s1 = fmaf(w1.x, b1.x, s1); s1 = fmaf(w1.y, b1.y, s1);
                s1 = fmaf(w1.z, b1.z, s1); s1 = fmaf(w1.w, b1.w, s1);
                // one f64 accumulate per 8 elements
                acc[e]     += (double)s0;
                acc[8 + e] += (double)s1;
            }
        }

        // reduce-scatter butterfly (verified round 6): masks 1,2,4,8 halve
        // 16 values/lane -> 1, then 16,32 finish. Bit-identical totals to
        // the full butterfly (same pairing, commutative adds).
        {
            const bool u1 = lane & 1;
#pragma unroll
            for (int i = 0; i < 8; ++i) {
                double send = u1 ? acc[i] : acc[8 + i];
                double got  = __shfl_xor(send, 1, 64);
                acc[i] = (u1 ? acc[8 + i] : acc[i]) + got;
            }
            const bool u2 = lane & 2;
#pragma unroll
            for (int i = 0; i < 4; ++i) {
                double send = u2 ? acc[i] : acc[4 + i];
                double got  = __shfl_xor(send, 2, 64);
                acc[i] = (u2 ? acc[4 + i] : acc[i]) + got;
            }
            const bool u4 = lane & 4;
#pragma unroll
            for (int i = 0; i < 2; ++i) {
                double send = u4 ? acc[i] : acc[2 + i];
                double got  = __shfl_xor(send, 4, 64);
                acc[i] = (u4 ? acc[2 + i] : acc[i]) + got;
            }
            const bool u8 = lane & 8;
            {
                double send = u8 ? acc[0] : acc[1];
                double got  = __shfl_xor(send, 8, 64);
                acc[0] = (u8 ? acc[1] : acc[0]) + got;
            }
            acc[0] += __shfl_xor(acc[0], 16, 64);
            acc[0] += __shfl_xor(acc[0], 32, 64);
        }
        // value j sits at lane bitrev4(j): token a (j=e) at r, token b at r+1
        double v0[NEXP], v1[NEXP];
#pragma unroll
        for (int e = 0; e < NEXP; ++e) {
            const int r = ((e & 1) << 3) | ((e & 2) << 1) | ((e & 4) >> 1);
            v0[e] = __shfl(acc[0], r,     64);
            v1[e] = __shfl(acc[0], r + 1, 64);
        }
        if (lane == 0) {
            emit_token(v0, t0,     out, &cnt);
            emit_token(v1, t0 + 1, out, &cnt);
        }
    }

    // block histogram: reuse wlds as scratch after all waves done with W
    __syncthreads();
    float* h = reinterpret_cast<float*>(wlds);
    if (tid < NEXP) h[tid] = 0.0f;
    __syncthreads();
    if (lane == 0) {
#pragma unroll
        for (int e = 0; e < NEXP; ++e) {
            const unsigned c = (cnt >> (4 * e)) & 0xFu;
            if (c) atomicAdd(&h[e], (float)c);
        }
    }
    __syncthreads();
    if (tid < NEXP) atomicAdd(&out[HIST_OFF + tid], h[tid]);
}

extern "C" void kernel_launch(void* const* d_in, const int* in_sizes, int n_in,
                              void* d_out, int out_size, void* d_ws, size_t ws_size,
                              hipStream_t stream) {
    const float* x = (const float*)d_in[0];
    const float* W = (const float*)d_in[1];
    float* out = (float*)d_out;

    zero_hist_kernel<<<1, 64, 0, stream>>>(out);
    router_kernel<<<GRID, BLOCK, 0, stream>>>(x, W, out);
}